// Round 1
// baseline (385.456 us; speedup 1.0000x reference)
//
#include <hip/hip_runtime.h>
#include <math.h>

// Problem constants (from reference)
constexpr int   NN     = 50000;   // nodes
constexpr int   IN_DIM = 128;
constexpr int   HID    = 64;
constexpr int   NE     = 800000;  // edges
constexpr int   NM     = NE + NN; // messages incl. self loops
constexpr float ALPHA  = 0.1520f;
constexpr float BETA   = 0.7900f;

// ---------------- degree / norm ----------------
__global__ void k_init_deg(float* __restrict__ deg) {
    int i = blockIdx.x * blockDim.x + threadIdx.x;
    if (i < NN) deg[i] = 1.0f;  // self loop
}

__global__ void k_accum_deg(const int* __restrict__ row, float* __restrict__ deg) {
    int e = blockIdx.x * blockDim.x + threadIdx.x;
    if (e < NE) atomicAdd(&deg[row[e]], 1.0f);
}

__global__ void k_dinv(float* __restrict__ deg) {
    int i = blockIdx.x * blockDim.x + threadIdx.x;
    if (i < NN) deg[i] = rsqrtf(deg[i]);  // deg >= 1 always
}

// ---------------- GEMM1: h = feat @ W1  (no bias here) ----------------
// block = 256 threads, 16 nodes per block. W1 (128x64 = 32KB) + feat tile (8KB) in LDS.
__global__ __launch_bounds__(256) void k_gemm1(const float* __restrict__ feat,
                                               const float* __restrict__ W1,
                                               float* __restrict__ h) {
    __shared__ float sW[IN_DIM * HID];   // 8192 floats
    __shared__ float sF[16][IN_DIM];     // 2048 floats
    int t = threadIdx.x;

    const float4* W4  = (const float4*)W1;
    float4*       sW4 = (float4*)sW;
#pragma unroll
    for (int i = 0; i < 8; ++i) sW4[t + i * 256] = W4[t + i * 256];

    int n0 = blockIdx.x * 16;
    const float4* F4  = (const float4*)(feat + (size_t)n0 * IN_DIM);
    float4*       sF4 = (float4*)&sF[0][0];
    sF4[t]       = F4[t];
    sF4[t + 256] = F4[t + 256];
    __syncthreads();

    int c = t & 63;        // output channel
    int g = t >> 6;        // node group 0..3 (nodes g*4 .. g*4+3)
    float acc[4] = {0.f, 0.f, 0.f, 0.f};
    for (int k = 0; k < IN_DIM; ++k) {
        float w = sW[k * HID + c];
#pragma unroll
        for (int i = 0; i < 4; ++i) acc[i] += sF[g * 4 + i][k] * w;
    }
#pragma unroll
    for (int i = 0; i < 4; ++i) {
        int n = n0 + g * 4 + i;
        h[(size_t)n * HID + c] = acc[i];
    }
}

// ---------------- scatter layer 1: agg[row] += h[col] * norm ----------------
// one wave (64 lanes) per message, lane = channel
__global__ __launch_bounds__(256) void k_scatter1(const int* __restrict__ row,
                                                  const int* __restrict__ col,
                                                  const float* __restrict__ dinv,
                                                  const float* __restrict__ h,
                                                  float* __restrict__ agg) {
    long long gid = (long long)blockIdx.x * blockDim.x + threadIdx.x;
    int m = (int)(gid >> 6);
    int c = (int)(gid & 63);
    if (m >= NM) return;
    int r, cl;
    if (m < NE) { r = row[m]; cl = col[m]; }
    else        { r = cl = m - NE; }
    float nrm = dinv[r] * dinv[cl];
    float v = h[(size_t)cl * HID + c] * nrm;
    atomicAdd(&agg[(size_t)r * HID + c], v);
}

// ---------------- relu(agg + b1) in place ----------------
__global__ void k_relu_bias(float* __restrict__ agg, const float* __restrict__ b1) {
    int i = blockIdx.x * blockDim.x + threadIdx.x;
    if (i < NN * HID) {
        float v = agg[i] + b1[i & 63];
        agg[i] = v > 0.f ? v : 0.f;
    }
}

// ---------------- GEMM2: h2 = h1 @ W2  (64 -> 2, no bias) ----------------
__global__ void k_gemm2(const float* __restrict__ h1, const float* __restrict__ W2,
                        float* __restrict__ h2) {
    __shared__ float sW[HID * 2];
    int t = threadIdx.x;
    if (t < HID * 2) sW[t] = W2[t];
    __syncthreads();
    int n = blockIdx.x * blockDim.x + t;
    if (n >= NN) return;
    const float4* r4 = (const float4*)(h1 + (size_t)n * HID);
    float a0 = 0.f, a1 = 0.f;
#pragma unroll
    for (int k4 = 0; k4 < HID / 4; ++k4) {
        float4 v = r4[k4];
        int k = k4 * 4;
        a0 += v.x * sW[(k + 0) * 2 + 0] + v.y * sW[(k + 1) * 2 + 0]
            + v.z * sW[(k + 2) * 2 + 0] + v.w * sW[(k + 3) * 2 + 0];
        a1 += v.x * sW[(k + 0) * 2 + 1] + v.y * sW[(k + 1) * 2 + 1]
            + v.z * sW[(k + 2) * 2 + 1] + v.w * sW[(k + 3) * 2 + 1];
    }
    h2[(size_t)n * 2 + 0] = a0;
    h2[(size_t)n * 2 + 1] = a1;
}

// ---------------- scatter layer 2: emb[row] += h2[col] * norm ----------------
__global__ void k_scatter2(const int* __restrict__ row, const int* __restrict__ col,
                           const float* __restrict__ dinv,
                           const float* __restrict__ h2, float* __restrict__ emb) {
    int m = blockIdx.x * blockDim.x + threadIdx.x;
    if (m >= NM) return;
    int r, cl;
    if (m < NE) { r = row[m]; cl = col[m]; }
    else        { r = cl = m - NE; }
    float nrm = dinv[r] * dinv[cl];
    atomicAdd(&emb[(size_t)r * 2 + 0], h2[(size_t)cl * 2 + 0] * nrm);
    atomicAdd(&emb[(size_t)r * 2 + 1], h2[(size_t)cl * 2 + 1] * nrm);
}

// ---------------- emb += b2 ----------------
__global__ void k_bias2(float* __restrict__ emb, const float* __restrict__ b2) {
    int i = blockIdx.x * blockDim.x + threadIdx.x;
    if (i < NN * 2) emb[i] += b2[i & 1];
}

// ---------------- q = 1/(1 + alpha * d^(2*beta)) ----------------
__global__ void k_q(const int* __restrict__ pr, const int* __restrict__ pc,
                    const int* __restrict__ nr, const int* __restrict__ nc,
                    const float* __restrict__ emb, float* __restrict__ q) {
    int e = blockIdx.x * blockDim.x + threadIdx.x;
    if (e >= 2 * NE) return;
    int a, b;
    if (e < NE) { a = pr[e]; b = pc[e]; }
    else        { a = nr[e - NE]; b = nc[e - NE]; }
    float ax = emb[(size_t)a * 2 + 0], ay = emb[(size_t)a * 2 + 1];
    float bx = emb[(size_t)b * 2 + 0], by = emb[(size_t)b * 2 + 1];
    float dx = ax - bx, dy = ay - by;
    float d = sqrtf(dx * dx + dy * dy + 1e-12f);
    q[e] = 1.0f / (1.0f + ALPHA * powf(d, 2.0f * BETA));
}

extern "C" void kernel_launch(void* const* d_in, const int* in_sizes, int n_in,
                              void* d_out, int out_size, void* d_ws, size_t ws_size,
                              hipStream_t stream) {
    const float* feat = (const float*)d_in[0];
    const float* W1   = (const float*)d_in[1];
    const float* b1   = (const float*)d_in[2];
    const float* W2   = (const float*)d_in[3];
    const float* b2   = (const float*)d_in[4];
    const int*   ei   = (const int*)d_in[5];   // [2, NE] flat: row then col
    const int*   nrw  = (const int*)d_in[6];
    const int*   ncl  = (const int*)d_in[7];
    const int* row = ei;
    const int* col = ei + NE;

    float* ws   = (float*)d_ws;
    float* deg  = ws;                       // [NN]   (becomes dinv in place)
    float* h1   = ws + NN;                  // [NN*64]
    float* agg1 = ws + NN + (size_t)NN * HID;        // [NN*64]
    float* h2   = ws + NN + (size_t)2 * NN * HID;    // [NN*2]

    float* emb = (float*)d_out;             // [NN*2]
    float* q   = (float*)d_out + (size_t)NN * 2;  // [2*NE]

    // zero accumulators
    hipMemsetAsync(agg1, 0, (size_t)NN * HID * sizeof(float), stream);
    hipMemsetAsync(emb, 0, (size_t)NN * 2 * sizeof(float), stream);

    k_init_deg<<<(NN + 255) / 256, 256, 0, stream>>>(deg);
    k_accum_deg<<<(NE + 255) / 256, 256, 0, stream>>>(row, deg);
    k_dinv<<<(NN + 255) / 256, 256, 0, stream>>>(deg);

    k_gemm1<<<NN / 16, 256, 0, stream>>>(feat, W1, h1);

    long long th1 = (long long)NM * 64;
    k_scatter1<<<(unsigned)((th1 + 255) / 256), 256, 0, stream>>>(row, col, deg, h1, agg1);

    k_relu_bias<<<(NN * HID + 255) / 256, 256, 0, stream>>>(agg1, b1);

    k_gemm2<<<(NN + 255) / 256, 256, 0, stream>>>(agg1, W2, h2);

    k_scatter2<<<(NM + 255) / 256, 256, 0, stream>>>(row, col, deg, h2, emb);

    k_bias2<<<(NN * 2 + 255) / 256, 256, 0, stream>>>(emb, b2);

    k_q<<<(2 * NE + 255) / 256, 256, 0, stream>>>(row, col, nrw, ncl, emb, q);
}

// Round 3
// 241.844 us; speedup vs baseline: 1.5938x; 1.5938x over previous
//
#include <hip/hip_runtime.h>
#include <math.h>

constexpr int   NN     = 50000;   // nodes
constexpr int   IN_DIM = 128;
constexpr int   HID    = 64;
constexpr int   NE     = 800000;  // edges
constexpr float ALPHA  = 0.1520f;
constexpr float BETA   = 0.7900f;

constexpr int SCAN_BLOCKS = (NN + 255) / 256;  // 196

// ---------------- edge count per destination row ----------------
__global__ void k_count(const int* __restrict__ row, int* __restrict__ ec) {
    int e = blockIdx.x * blockDim.x + threadIdx.x;
    if (e < NE) atomicAdd(&ec[row[e]], 1);
}

// ---------------- dinv = rsqrt(ec + 1)  (self loop) ----------------
__global__ void k_dinv(const int* __restrict__ ec, float* __restrict__ dinv) {
    int i = blockIdx.x * blockDim.x + threadIdx.x;
    if (i < NN) dinv[i] = rsqrtf((float)(ec[i] + 1));
}

// ---------------- 3-phase exclusive scan of ec -> offs ----------------
__global__ void k_scan1(const int* __restrict__ ec, int* __restrict__ loc,
                        int* __restrict__ part) {
    __shared__ int s[256];
    int t = threadIdx.x;
    int i = blockIdx.x * 256 + t;
    int v = (i < NN) ? ec[i] : 0;
    s[t] = v;
    __syncthreads();
    for (int d = 1; d < 256; d <<= 1) {
        int u = (t >= d) ? s[t - d] : 0;
        __syncthreads();
        s[t] += u;
        __syncthreads();
    }
    if (i < NN) loc[i] = s[t] - v;            // exclusive within block
    if (t == 255) part[blockIdx.x] = s[255];  // block total
}

__global__ void k_scan2(int* __restrict__ part) {  // single block of 256
    __shared__ int s[256];
    int t = threadIdx.x;
    int v = (t < SCAN_BLOCKS) ? part[t] : 0;
    s[t] = v;
    __syncthreads();
    for (int d = 1; d < 256; d <<= 1) {
        int u = (t >= d) ? s[t - d] : 0;
        __syncthreads();
        s[t] += u;
        __syncthreads();
    }
    if (t < SCAN_BLOCKS) part[t] = s[t] - v;  // exclusive block offsets
}

__global__ void k_scan3(const int* __restrict__ loc, const int* __restrict__ part,
                        int* __restrict__ offs, int* __restrict__ cursor) {
    int i = blockIdx.x * blockDim.x + threadIdx.x;
    if (i < NN) {
        int o = loc[i] + part[i >> 8];
        offs[i]   = o;
        cursor[i] = o;
    }
    if (i == 0) offs[NN] = NE;
}

// ---------------- CSR fill: cols per destination ----------------
__global__ void k_fill(const int* __restrict__ row, const int* __restrict__ col,
                       int* __restrict__ cursor, int* __restrict__ scol) {
    int e = blockIdx.x * blockDim.x + threadIdx.x;
    if (e < NE) {
        int p = atomicAdd(&cursor[row[e]], 1);
        scol[p] = col[e];
    }
}

// ---------------- GEMM1: h1 = feat @ W1 ----------------
__global__ __launch_bounds__(256) void k_gemm1(const float* __restrict__ feat,
                                               const float* __restrict__ W1,
                                               float* __restrict__ h) {
    __shared__ float sW[IN_DIM * HID];
    __shared__ float sF[16][IN_DIM];
    int t = threadIdx.x;

    const float4* W4  = (const float4*)W1;
    float4*       sW4 = (float4*)sW;
#pragma unroll
    for (int i = 0; i < 8; ++i) sW4[t + i * 256] = W4[t + i * 256];

    int n0 = blockIdx.x * 16;
    const float4* F4  = (const float4*)(feat + (size_t)n0 * IN_DIM);
    float4*       sF4 = (float4*)&sF[0][0];
    sF4[t]       = F4[t];
    sF4[t + 256] = F4[t + 256];
    __syncthreads();

    int c = t & 63;
    int g = t >> 6;
    float acc[4] = {0.f, 0.f, 0.f, 0.f};
    for (int k = 0; k < IN_DIM; ++k) {
        float w = sW[k * HID + c];
#pragma unroll
        for (int i = 0; i < 4; ++i) acc[i] += sF[g * 4 + i][k] * w;
    }
#pragma unroll
    for (int i = 0; i < 4; ++i) {
        int n = n0 + g * 4 + i;
        h[(size_t)n * HID + c] = acc[i];
    }
}

// ---------------- fused: agg1 = gather(h1), relu(+b1), @W2 -> h2 ----------------
// one wave per node, lane = hidden channel
__global__ __launch_bounds__(256) void k_agg1(const int* __restrict__ offs,
                                              const int* __restrict__ scol,
                                              const float* __restrict__ dinv,
                                              const float* __restrict__ h1,
                                              const float* __restrict__ b1,
                                              const float* __restrict__ W2,
                                              float* __restrict__ h2) {
    int n    = blockIdx.x * 4 + (threadIdx.x >> 6);
    int lane = threadIdx.x & 63;
    if (n >= NN) return;
    int beg = offs[n], end = offs[n + 1];
    float acc = 0.f;
    for (int k = beg; k < end; ++k) {
        int cl = scol[k];
        acc += dinv[cl] * h1[(size_t)cl * HID + lane];
    }
    float di = dinv[n];
    acc = di * (acc + di * h1[(size_t)n * HID + lane]);   // + self loop, * dinv[row]
    acc += b1[lane];
    acc = fmaxf(acc, 0.f);
    // GEMM2 via wave reduction
    float p0 = acc * W2[lane * 2 + 0];
    float p1 = acc * W2[lane * 2 + 1];
#pragma unroll
    for (int d = 32; d >= 1; d >>= 1) {
        p0 += __shfl_xor(p0, d);
        p1 += __shfl_xor(p1, d);
    }
    if (lane == 0) {
        h2[(size_t)n * 2 + 0] = p0;
        h2[(size_t)n * 2 + 1] = p1;
    }
}

// ---------------- fused: emb = gather(h2) + b2 ----------------
// one wave per node, lanes parallel over edges
__global__ __launch_bounds__(256) void k_agg2(const int* __restrict__ offs,
                                              const int* __restrict__ scol,
                                              const float* __restrict__ dinv,
                                              const float* __restrict__ h2,
                                              const float* __restrict__ b2,
                                              float* __restrict__ emb) {
    int n    = blockIdx.x * 4 + (threadIdx.x >> 6);
    int lane = threadIdx.x & 63;
    if (n >= NN) return;
    int beg = offs[n], end = offs[n + 1];
    float e0 = 0.f, e1 = 0.f;
    for (int k = beg + lane; k < end; k += 64) {
        int cl = scol[k];
        float dc = dinv[cl];
        e0 += dc * h2[(size_t)cl * 2 + 0];
        e1 += dc * h2[(size_t)cl * 2 + 1];
    }
#pragma unroll
    for (int d = 32; d >= 1; d >>= 1) {
        e0 += __shfl_xor(e0, d);
        e1 += __shfl_xor(e1, d);
    }
    if (lane == 0) {
        float di = dinv[n];
        emb[(size_t)n * 2 + 0] = di * (e0 + di * h2[(size_t)n * 2 + 0]) + b2[0];
        emb[(size_t)n * 2 + 1] = di * (e1 + di * h2[(size_t)n * 2 + 1]) + b2[1];
    }
}

// ---------------- q = 1/(1 + alpha * d^(2*beta)) ----------------
__global__ void k_q(const int* __restrict__ pr, const int* __restrict__ pc,
                    const int* __restrict__ nr, const int* __restrict__ nc,
                    const float* __restrict__ emb, float* __restrict__ q) {
    int e = blockIdx.x * blockDim.x + threadIdx.x;
    if (e >= 2 * NE) return;
    int a, b;
    if (e < NE) { a = pr[e]; b = pc[e]; }
    else        { a = nr[e - NE]; b = nc[e - NE]; }
    float ax = emb[(size_t)a * 2 + 0], ay = emb[(size_t)a * 2 + 1];
    float bx = emb[(size_t)b * 2 + 0], by = emb[(size_t)b * 2 + 1];
    float dx = ax - bx, dy = ay - by;
    float d = sqrtf(dx * dx + dy * dy + 1e-12f);
    float p = exp2f(2.0f * BETA * log2f(d));
    q[e] = 1.0f / (1.0f + ALPHA * p);
}

extern "C" void kernel_launch(void* const* d_in, const int* in_sizes, int n_in,
                              void* d_out, int out_size, void* d_ws, size_t ws_size,
                              hipStream_t stream) {
    const float* feat = (const float*)d_in[0];
    const float* W1   = (const float*)d_in[1];
    const float* b1   = (const float*)d_in[2];
    const float* W2   = (const float*)d_in[3];
    const float* b2   = (const float*)d_in[4];
    const int*   ei   = (const int*)d_in[5];
    const int*   nrw  = (const int*)d_in[6];
    const int*   ncl  = (const int*)d_in[7];
    const int* row = ei;
    const int* col = ei + NE;

    char* w = (char*)d_ws;
    int*   ec     = (int*)w;                 w += sizeof(int) * (NN + 256);
    int*   loc    = (int*)w;                 w += sizeof(int) * (NN + 256);
    int*   part   = (int*)w;                 w += sizeof(int) * 256;
    int*   offs   = (int*)w;                 w += sizeof(int) * (NN + 1);
    int*   cursor = (int*)w;                 w += sizeof(int) * NN;
    float* dinv   = (float*)w;               w += sizeof(float) * NN;
    int*   scol   = (int*)w;                 w += sizeof(int) * NE;
    float* h1     = (float*)w;               w += sizeof(float) * (size_t)NN * HID;
    float* h2     = (float*)w;               w += sizeof(float) * (size_t)NN * 2;

    float* emb = (float*)d_out;
    float* q   = (float*)d_out + (size_t)NN * 2;

    hipError_t _e = hipMemsetAsync(ec, 0, sizeof(int) * NN, stream);
    (void)_e;

    k_count<<<(NE + 255) / 256, 256, 0, stream>>>(row, ec);
    k_dinv <<<(NN + 255) / 256, 256, 0, stream>>>(ec, dinv);
    k_scan1<<<SCAN_BLOCKS, 256, 0, stream>>>(ec, loc, part);
    k_scan2<<<1, 256, 0, stream>>>(part);
    k_scan3<<<SCAN_BLOCKS, 256, 0, stream>>>(loc, part, offs, cursor);
    k_fill <<<(NE + 255) / 256, 256, 0, stream>>>(row, col, cursor, scol);

    k_gemm1<<<NN / 16, 256, 0, stream>>>(feat, W1, h1);

    k_agg1<<<(NN + 3) / 4, 256, 0, stream>>>(offs, scol, dinv, h1, b1, W2, h2);
    k_agg2<<<(NN + 3) / 4, 256, 0, stream>>>(offs, scol, dinv, h2, b2, emb);

    k_q<<<(2 * NE + 255) / 256, 256, 0, stream>>>(row, col, nrw, ncl, emb, q);
}

// Round 4
// 193.395 us; speedup vs baseline: 1.9931x; 1.2505x over previous
//
#include <hip/hip_runtime.h>
#include <hip/hip_fp16.h>
#include <math.h>

constexpr int   NN     = 50000;   // nodes
constexpr int   IN_DIM = 128;
constexpr int   HID    = 64;
constexpr int   NE     = 800000;  // edges
constexpr float ALPHA  = 0.1520f;
constexpr float BETA   = 0.7900f;

constexpr int SCAN_BLOCKS = (NN + 255) / 256;  // 196

// ---------------- edge count per destination row ----------------
__global__ void k_count(const int* __restrict__ row, int* __restrict__ ec) {
    int e = blockIdx.x * blockDim.x + threadIdx.x;
    if (e < NE) atomicAdd(&ec[row[e]], 1);
}

// ---------------- scan phase 1 (+ dinv fused) ----------------
__global__ void k_scan1(const int* __restrict__ ec, int* __restrict__ loc,
                        int* __restrict__ part, float* __restrict__ dinv) {
    __shared__ int s[256];
    int t = threadIdx.x;
    int i = blockIdx.x * 256 + t;
    int v = (i < NN) ? ec[i] : 0;
    if (i < NN) dinv[i] = rsqrtf((float)(v + 1));  // self loop included
    s[t] = v;
    __syncthreads();
    for (int d = 1; d < 256; d <<= 1) {
        int u = (t >= d) ? s[t - d] : 0;
        __syncthreads();
        s[t] += u;
        __syncthreads();
    }
    if (i < NN) loc[i] = s[t] - v;            // exclusive within block
    if (t == 255) part[blockIdx.x] = s[255];  // block total
}

__global__ void k_scan2(int* __restrict__ part) {  // single block of 256
    __shared__ int s[256];
    int t = threadIdx.x;
    int v = (t < SCAN_BLOCKS) ? part[t] : 0;
    s[t] = v;
    __syncthreads();
    for (int d = 1; d < 256; d <<= 1) {
        int u = (t >= d) ? s[t - d] : 0;
        __syncthreads();
        s[t] += u;
        __syncthreads();
    }
    if (t < SCAN_BLOCKS) part[t] = s[t] - v;  // exclusive block offsets
}

__global__ void k_scan3(const int* __restrict__ loc, const int* __restrict__ part,
                        int* __restrict__ offs, int* __restrict__ cursor) {
    int i = blockIdx.x * blockDim.x + threadIdx.x;
    if (i < NN) {
        int o = loc[i] + part[i >> 8];
        offs[i]   = o;
        cursor[i] = o;
    }
    if (i == 0) offs[NN] = NE;
}

// ---------------- CSR fill ----------------
__global__ void k_fill(const int* __restrict__ row, const int* __restrict__ col,
                       int* __restrict__ cursor, int* __restrict__ scol) {
    int e = blockIdx.x * blockDim.x + threadIdx.x;
    if (e < NE) {
        int p = atomicAdd(&cursor[row[e]], 1);
        scol[p] = col[e];
    }
}

// ---------------- GEMM1: h1s = fp16( dinv[n] * (feat @ W1) ) ----------------
__global__ __launch_bounds__(256) void k_gemm1(const float* __restrict__ feat,
                                               const float* __restrict__ W1,
                                               const float* __restrict__ dinv,
                                               __half* __restrict__ h1s) {
    __shared__ float sW[IN_DIM * HID];
    __shared__ float sF[16][IN_DIM];
    int t = threadIdx.x;

    const float4* W4  = (const float4*)W1;
    float4*       sW4 = (float4*)sW;
#pragma unroll
    for (int i = 0; i < 8; ++i) sW4[t + i * 256] = W4[t + i * 256];

    int n0 = blockIdx.x * 16;
    const float4* F4  = (const float4*)(feat + (size_t)n0 * IN_DIM);
    float4*       sF4 = (float4*)&sF[0][0];
    sF4[t]       = F4[t];
    sF4[t + 256] = F4[t + 256];
    __syncthreads();

    int c = t & 63;
    int g = t >> 6;
    float acc[4] = {0.f, 0.f, 0.f, 0.f};
    for (int k = 0; k < IN_DIM; ++k) {
        float w = sW[k * HID + c];
#pragma unroll
        for (int i = 0; i < 4; ++i) acc[i] += sF[g * 4 + i][k] * w;
    }
#pragma unroll
    for (int i = 0; i < 4; ++i) {
        int n = n0 + g * 4 + i;
        h1s[(size_t)n * HID + c] = __float2half(acc[i] * dinv[n]);
    }
}

// ---------------- fused: agg1(gather) + b1 + relu + @W2 -> h2s (pre-scaled) ----------------
// one wave per node, lane = hidden channel; 4-way unrolled edge loop for ILP
__global__ __launch_bounds__(256) void k_agg1(const int* __restrict__ offs,
                                              const int* __restrict__ scol,
                                              const float* __restrict__ dinv,
                                              const __half* __restrict__ h1s,
                                              const float* __restrict__ b1,
                                              const float* __restrict__ W2,
                                              float* __restrict__ h2s) {
    int n    = blockIdx.x * 4 + (threadIdx.x >> 6);
    int lane = threadIdx.x & 63;
    if (n >= NN) return;
    int beg = offs[n], end = offs[n + 1];
    float acc = 0.f;
    int k = beg;
    for (; k + 3 < end; k += 4) {
        int c0 = scol[k], c1 = scol[k + 1], c2 = scol[k + 2], c3 = scol[k + 3];
        float v0 = __half2float(h1s[(size_t)c0 * HID + lane]);
        float v1 = __half2float(h1s[(size_t)c1 * HID + lane]);
        float v2 = __half2float(h1s[(size_t)c2 * HID + lane]);
        float v3 = __half2float(h1s[(size_t)c3 * HID + lane]);
        acc += (v0 + v1) + (v2 + v3);
    }
    for (; k < end; ++k)
        acc += __half2float(h1s[(size_t)scol[k] * HID + lane]);

    float di = dinv[n];
    acc = di * (acc + __half2float(h1s[(size_t)n * HID + lane]));  // + self loop
    acc += b1[lane];
    acc = fmaxf(acc, 0.f);
    // GEMM2 via wave reduction; write pre-scaled h2s = dinv[n] * (relu @ W2)
    float p0 = acc * W2[lane * 2 + 0];
    float p1 = acc * W2[lane * 2 + 1];
#pragma unroll
    for (int d = 32; d >= 1; d >>= 1) {
        p0 += __shfl_xor(p0, d);
        p1 += __shfl_xor(p1, d);
    }
    if (lane == 0) {
        h2s[(size_t)n * 2 + 0] = di * p0;
        h2s[(size_t)n * 2 + 1] = di * p1;
    }
}

// ---------------- fused: emb = dinv[n]*(gather(h2s)+self) + b2 ----------------
__global__ __launch_bounds__(256) void k_agg2(const int* __restrict__ offs,
                                              const int* __restrict__ scol,
                                              const float* __restrict__ dinv,
                                              const float* __restrict__ h2s,
                                              const float* __restrict__ b2,
                                              float* __restrict__ emb) {
    int n    = blockIdx.x * 4 + (threadIdx.x >> 6);
    int lane = threadIdx.x & 63;
    if (n >= NN) return;
    int beg = offs[n], end = offs[n + 1];
    float e0 = 0.f, e1 = 0.f;
    const float2* h22 = (const float2*)h2s;
    for (int k = beg + lane; k < end; k += 64) {
        float2 v = h22[scol[k]];
        e0 += v.x;
        e1 += v.y;
    }
#pragma unroll
    for (int d = 32; d >= 1; d >>= 1) {
        e0 += __shfl_xor(e0, d);
        e1 += __shfl_xor(e1, d);
    }
    if (lane == 0) {
        float di = dinv[n];
        float2 self = h22[n];
        emb[(size_t)n * 2 + 0] = di * (e0 + self.x) + b2[0];
        emb[(size_t)n * 2 + 1] = di * (e1 + self.y) + b2[1];
    }
}

// ---------------- q = 1/(1 + alpha * d^(2*beta)) ----------------
__global__ void k_q(const int* __restrict__ pr, const int* __restrict__ pc,
                    const int* __restrict__ nr, const int* __restrict__ nc,
                    const float* __restrict__ emb, float* __restrict__ q) {
    int e = blockIdx.x * blockDim.x + threadIdx.x;
    if (e >= 2 * NE) return;
    int a, b;
    if (e < NE) { a = pr[e]; b = pc[e]; }
    else        { a = nr[e - NE]; b = nc[e - NE]; }
    const float2* e2 = (const float2*)emb;
    float2 A = e2[a], B = e2[b];
    float dx = A.x - B.x, dy = A.y - B.y;
    float d = sqrtf(dx * dx + dy * dy + 1e-12f);
    float p = exp2f(2.0f * BETA * log2f(d));
    q[e] = 1.0f / (1.0f + ALPHA * p);
}

extern "C" void kernel_launch(void* const* d_in, const int* in_sizes, int n_in,
                              void* d_out, int out_size, void* d_ws, size_t ws_size,
                              hipStream_t stream) {
    const float* feat = (const float*)d_in[0];
    const float* W1   = (const float*)d_in[1];
    const float* b1   = (const float*)d_in[2];
    const float* W2   = (const float*)d_in[3];
    const float* b2   = (const float*)d_in[4];
    const int*   ei   = (const int*)d_in[5];
    const int*   nrw  = (const int*)d_in[6];
    const int*   ncl  = (const int*)d_in[7];
    const int* row = ei;
    const int* col = ei + NE;

    char* w = (char*)d_ws;
    int*    ec     = (int*)w;     w += sizeof(int) * (NN + 256);
    int*    loc    = (int*)w;     w += sizeof(int) * (NN + 256);
    int*    part   = (int*)w;     w += sizeof(int) * 256;
    int*    offs   = (int*)w;     w += sizeof(int) * (NN + 1);
    int*    cursor = (int*)w;     w += sizeof(int) * NN;
    float*  dinv   = (float*)w;   w += sizeof(float) * NN;
    int*    scol   = (int*)w;     w += sizeof(int) * NE;
    float*  h2s    = (float*)w;   w += sizeof(float) * (size_t)NN * 2;
    __half* h1s    = (__half*)w;  w += sizeof(__half) * (size_t)NN * HID;

    float* emb = (float*)d_out;
    float* q   = (float*)d_out + (size_t)NN * 2;

    hipError_t _e = hipMemsetAsync(ec, 0, sizeof(int) * NN, stream);
    (void)_e;

    k_count<<<(NE + 255) / 256, 256, 0, stream>>>(row, ec);
    k_scan1<<<SCAN_BLOCKS, 256, 0, stream>>>(ec, loc, part, dinv);
    k_scan2<<<1, 256, 0, stream>>>(part);
    k_scan3<<<SCAN_BLOCKS, 256, 0, stream>>>(loc, part, offs, cursor);
    k_fill <<<(NE + 255) / 256, 256, 0, stream>>>(row, col, cursor, scol);

    k_gemm1<<<NN / 16, 256, 0, stream>>>(feat, W1, dinv, h1s);

    k_agg1<<<(NN + 3) / 4, 256, 0, stream>>>(offs, scol, dinv, h1s, b1, W2, h2s);
    k_agg2<<<(NN + 3) / 4, 256, 0, stream>>>(offs, scol, dinv, h2s, b2, emb);

    k_q<<<(2 * NE + 255) / 256, 256, 0, stream>>>(row, col, nrw, ncl, emb, q);
}